// Round 11
// baseline (226.138 us; speedup 1.0000x reference)
//
#include <hip/hip_runtime.h>
#include <hip/hip_bf16.h>

typedef __attribute__((ext_vector_type(8))) short short8;
typedef __attribute__((ext_vector_type(4))) float f32x4;
typedef __hip_bfloat16 bf16;

static constexpr int T_TOK = 8192;   // B*S
static constexpr int HD    = 2048;
static constexpr int FD    = 8192;
static constexpr int NE    = 8;

#define MFMA16(a,b,c) __builtin_amdgcn_mfma_f32_16x16x32_bf16((a),(b),(c),0,0,0)

// ---------------- K0: weight convert + pack, zero counts ----------------
__global__ __launch_bounds__(256) void k_convert(
    const float* __restrict__ w1A, const float* __restrict__ w1B,
    const float* __restrict__ w2A, const float* __restrict__ w2B,
    const float* __restrict__ w3A, const float* __restrict__ w3B,
    bf16* __restrict__ bw1a3, bf16* __restrict__ bw1b, bf16* __restrict__ bw3b,
    bf16* __restrict__ bw2apk, bf16* __restrict__ bw2b, int* __restrict__ cnt)
{
  int i = blockIdx.x * 256 + threadIdx.x;          // 0 .. 1048575
  if (blockIdx.x == 0 && threadIdx.x < 16) cnt[threadIdx.x] = 0;
  // straight casts of w1_B / w3_B  [E][F][R] = 1048576 elems
  bw1b[i] = __float2bfloat16(w1B[i]);
  bw3b[i] = __float2bfloat16(w3B[i]);
  { // w2_A [E][R][F] -> A-frag pack for swapped contraction:
    // element j of lane (lg*16+r) in 32-f group ft: f = ft*32+(j>>2)*16+lg*4+(j&3)
    int f = i & (FD - 1); int er = i >> 13; int e = er >> 4; int r = er & 15;
    int ft = f >> 5; int fo = f & 31;
    int sub = fo >> 4; int lg = (fo >> 2) & 3; int j = sub * 4 + (fo & 3);
    int lane = lg * 16 + r;
    bw2apk[((e * 256 + ft) * 64 + lane) * 8 + j] = __float2bfloat16(w2A[i]);
  }
  if (i < 256 * HD) { // pack [w1A;w3A] -> [e][kk(64)][rr(32)][kc(32)]  (2KB tiles)
    int h = i & (HD - 1); int nn = i >> 11; int e = nn >> 5; int rr = nn & 31;
    float v = (rr < 16) ? w1A[(e * 16 + rr) * HD + h] : w3A[(e * 16 + (rr - 16)) * HD + h];
    bw1a3[e * 65536 + (h >> 5) * 1024 + rr * 32 + (h & 31)] = __float2bfloat16(v);
  }
  if (i < NE * HD * 16) bw2b[i] = __float2bfloat16(w2B[i]);  // [E][H][R] cast
}

// ---------------- K1+K2 fused: dense stage-1 + fp32 router + gather ----------------
// 512 blocks x 256 threads (4 waves), 4 blocks/CU target. 16 tokens/block; wave w
// does H-slice [w*512,(w+1)*512). Cross-wave reduce in 2 expert-halves (33.8 KB LDS).
__global__ __launch_bounds__(256, 4) void k_stage1(
    const float* __restrict__ x, const float* __restrict__ gw,
    const bf16* __restrict__ bw1a3, bf16* __restrict__ abuf,
    float* __restrict__ rw_out, int* __restrict__ cnt,
    int* __restrict__ tok, float* __restrict__ wl, int* __restrict__ selT)
{
  int tid = threadIdx.x;
  int w = tid >> 6, l = tid & 63, lm = l & 15, lg = l >> 4;
  int t0 = blockIdx.x * 16;

  __shared__ float redc[4][16 * 132];  // [wave][tok(16) x (128+4 pad)]  33.8 KB
  __shared__ float gred[4][16][8];     // gate partials per wave
  __shared__ float glog[16][8];
  __shared__ int   se0[16], se1[16];
  __shared__ float sw0[16], sw1[16];

  const float* xp = x + (size_t)(t0 + lm) * HD + w * 512 + lg * 8;
  f32x4 acc[8][2];
#pragma unroll
  for (int e = 0; e < 8; e++) { acc[e][0] = {0.f,0.f,0.f,0.f}; acc[e][1] = {0.f,0.f,0.f,0.f}; }
  float g[8];
#pragma unroll
  for (int e = 0; e < 8; e++) g[e] = 0.f;

#pragma unroll 2
  for (int kk2 = 0; kk2 < 16; kk2++) {
    float4 v0 = *reinterpret_cast<const float4*>(xp + kk2 * 32);
    float4 v1 = *reinterpret_cast<const float4*>(xp + kk2 * 32 + 4);
    // fp32 gate dot (exact router numerics); gw loads are wave-coherent (L2-hot)
    const float* gp = gw + w * 512 + kk2 * 32 + lg * 8;
#pragma unroll
    for (int e = 0; e < 8; e++) {
      float4 g0 = *reinterpret_cast<const float4*>(gp + e * HD);
      float4 g1 = *reinterpret_cast<const float4*>(gp + e * HD + 4);
      g[e] += v0.x * g0.x + v0.y * g0.y + v0.z * g0.z + v0.w * g0.w
            + v1.x * g1.x + v1.y * g1.y + v1.z * g1.z + v1.w * g1.w;
    }
    alignas(16) bf16 tmp[8];
    tmp[0] = __float2bfloat16(v0.x); tmp[1] = __float2bfloat16(v0.y);
    tmp[2] = __float2bfloat16(v0.z); tmp[3] = __float2bfloat16(v0.w);
    tmp[4] = __float2bfloat16(v1.x); tmp[5] = __float2bfloat16(v1.y);
    tmp[6] = __float2bfloat16(v1.z); tmp[7] = __float2bfloat16(v1.w);
    short8 af = *reinterpret_cast<const short8*>(tmp);
    const bf16* bt = bw1a3 + (w * 16 + kk2) * 1024 + lg * 8;
#pragma unroll
    for (int e = 0; e < 8; e++) {
      const bf16* be = bt + e * 65536;
      short8 b0 = *reinterpret_cast<const short8*>(be + lm * 32);
      short8 b1 = *reinterpret_cast<const short8*>(be + (lm + 16) * 32);
      acc[e][0] = MFMA16(af, b0, acc[e][0]);
      acc[e][1] = MFMA16(af, b1, acc[e][1]);
    }
  }
  // gate: in-wave reduce over lg (lanes lm, lm+16, lm+32, lm+48)
#pragma unroll
  for (int e = 0; e < 8; e++) {
    g[e] += __shfl_xor(g[e], 16);
    g[e] += __shfl_xor(g[e], 32);
  }
  if (lg == 0) {
#pragma unroll
    for (int e = 0; e < 8; e++) gred[w][lm][e] = g[e];
  }
  // cross-wave reduce + abuf store in 2 expert-halves (reuse redc)
#pragma unroll
  for (int half = 0; half < 2; half++) {
#pragma unroll
    for (int ei = 0; ei < 4; ei++) {
      int e = half * 4 + ei;
#pragma unroll
      for (int i = 0; i < 4; i++) {
        int tt = lg * 4 + i;
        redc[w][tt * 132 + ei * 32 + lm]      = acc[e][0][i];
        redc[w][tt * 132 + ei * 32 + 16 + lm] = acc[e][1][i];
      }
    }
    __syncthreads();
    int c = tid & 127, th = tid >> 7;
#pragma unroll
    for (int j8 = 0; j8 < 8; j8++) {
      int j = th * 8 + j8;
      int o = j * 132 + c;
      float s = redc[0][o] + redc[1][o] + redc[2][o] + redc[3][o];
      abuf[(size_t)(t0 + j) * (NE * 32) + half * 128 + c] = __float2bfloat16(s);
    }
    __syncthreads();
  }
  // gate finalize
  if (tid < 128) {
    int tk = tid >> 3, e = tid & 7;
    glog[tk][e] = gred[0][tk][e] + gred[1][tk][e] + gred[2][tk][e] + gred[3][tk][e];
  }
  __syncthreads();
  if (tid < 16) {
    int t = t0 + tid;
    float m = -1e30f;
#pragma unroll
    for (int e = 0; e < 8; e++) m = fmaxf(m, glog[tid][e]);
    float q[8];
#pragma unroll
    for (int e = 0; e < 8; e++) q[e] = __expf(glog[tid][e] - m);
    int i0 = 0; float b0 = q[0];
#pragma unroll
    for (int e = 1; e < 8; e++) if (q[e] > b0) { b0 = q[e]; i0 = e; }
    int i1 = -1; float b1 = -1.f;
#pragma unroll
    for (int e = 0; e < 8; e++) if (e != i0 && q[e] > b1) { b1 = q[e]; i1 = e; }
    float inv = 1.f / (b0 + b1);
    float r0 = b0 * inv, r1 = b1 * inv;
    rw_out[t * 2 + 0] = r0; rw_out[t * 2 + 1] = r1;
    selT[t] = i0 | (i1 << 8);
    se0[tid] = i0; se1[tid] = i1; sw0[tid] = r0; sw1[tid] = r1;
  }
  __syncthreads();
  if (tid < 16) {
    int ls = tid, e = ls >> 1, slot = ls & 1;
    int c = 0;
#pragma unroll
    for (int jj = 0; jj < 16; jj++)
      c += (slot == 0 ? (se0[jj] == e) : (se1[jj] == e)) ? 1 : 0;
    if (c > 0) {
      int base = atomicAdd(&cnt[ls], c);
      int k = 0;
#pragma unroll
      for (int jj = 0; jj < 16; jj++) {
        bool hit = (slot == 0 ? (se0[jj] == e) : (se1[jj] == e));
        if (hit) {
          tok[ls * T_TOK + base + k] = t0 + jj;
          wl [ls * T_TOK + base + k] = (slot == 0 ? sw0[jj] : sw1[jj]);
          k++;
        }
      }
    }
  }
}

// ---------------- K3: fused F-loop, 16 waves, dbuf prefetch, XCD swizzle ----------------
// 1024 threads / 16 waves; wave w owns F-slice [w*512,(w+1)*512); 64 pairs/block.
// blockIdx: xcd = b&7 -> expert (weights L2-local per XCD); pt = b>>4.
#define LDW(FT, B1, B3, W2) { \
    int f0_ = w * 512 + (FT) * 32; \
    _Pragma("unroll") \
    for (int sub = 0; sub < 2; sub++) { \
      int f_ = f0_ + sub * 16 + lm; \
      B1[sub] = *reinterpret_cast<const short8*>(w1e + f_ * 16 + r8); \
      B3[sub] = *reinterpret_cast<const short8*>(w3e + f_ * 16 + r8); \
    } \
    W2 = *reinterpret_cast<const short8*>(w2e + ((size_t)(f0_ >> 5) * 64 + l) * 8); }

#define CMP(B1, B3, W2) \
  _Pragma("unroll") \
  for (int m = 0; m < 4; m++) { \
    short8 hfrag; \
    _Pragma("unroll") \
    for (int sub = 0; sub < 2; sub++) { \
      f32x4 h1 = MFMA16(B1[sub], A1[m], zf); \
      f32x4 h3 = MFMA16(B3[sub], A3[m], zf); \
      _Pragma("unroll") \
      for (int i = 0; i < 4; i++) { \
        float a = h1[i]; \
        float hv = (a >= 0.f ? a : 0.01f * a) * h3[i]; \
        bf16 hb = __float2bfloat16(hv); \
        hfrag[sub * 4 + i] = *reinterpret_cast<short*>(&hb); \
      } \
    } \
    acc[m] = MFMA16(W2, hfrag, acc[m]); }

__global__ __launch_bounds__(1024) void k_fused(
    const bf16* __restrict__ abuf, const bf16* __restrict__ bw1b,
    const bf16* __restrict__ bw3b, const bf16* __restrict__ bw2apk,
    const int* __restrict__ cnt, const int* __restrict__ tok,
    const float* __restrict__ wl, bf16* __restrict__ accbf)
{
  int b = blockIdx.x;
  int ls = ((b & 7) << 1) | ((b >> 3) & 1);   // expert = XCD
  int pt = b >> 4;
  int n = cnt[ls]; int p0 = pt * 64;
  if (p0 >= n) return;
  int e = ls >> 1;
  int tid = threadIdx.x;
  int w = tid >> 6, l = tid & 63, lm = l & 15, lg = l >> 4;

  __shared__ float red[16][64 * 17];

  const short8 ZS = {0, 0, 0, 0, 0, 0, 0, 0};
  short8 A1[4], A3[4];   // B-operand of swapped MFMA: col=pair(lm), k=lg*8+j (zeros k>=16)
#pragma unroll
  for (int m = 0; m < 4; m++) {
    int pos = p0 + m * 16 + lm; if (pos > n - 1) pos = n - 1;
    int t = tok[ls * T_TOK + pos];
    const bf16* arow = abuf + ((size_t)t * NE + e) * 32;
    if (lg < 2) {
      A1[m] = *reinterpret_cast<const short8*>(arow + lg * 8);
      A3[m] = *reinterpret_cast<const short8*>(arow + 16 + lg * 8);
    } else { A1[m] = ZS; A3[m] = ZS; }
  }
  f32x4 acc[4];
#pragma unroll
  for (int m = 0; m < 4; m++) acc[m] = {0.f, 0.f, 0.f, 0.f};
  const f32x4 zf = {0.f, 0.f, 0.f, 0.f};
  int r8 = (lg & 1) * 8;                      // A-operand k-halves (k>=16 dup, B=0 there)
  const bf16* w1e = bw1b   + (size_t)e * FD * 16;
  const bf16* w3e = bw3b   + (size_t)e * FD * 16;
  const bf16* w2e = bw2apk + (size_t)e * 131072;

  short8 b1A[2], b3A[2], w2A_;
  short8 b1B[2], b3B[2], w2B_;
  LDW(0, b1A, b3A, w2A_);
  for (int ft = 0; ft < 16; ft += 2) {
    LDW(ft + 1, b1B, b3B, w2B_);
    CMP(b1A, b3A, w2A_);
    if (ft + 2 < 16) { LDW(ft + 2, b1A, b3A, w2A_); }
    CMP(b1B, b3B, w2B_);
  }
  // acc[m]: lane holds r = lg*4+i, pair = m*16+lm
#pragma unroll
  for (int m = 0; m < 4; m++)
#pragma unroll
    for (int i = 0; i < 4; i++)
      red[w][(m * 16 + lm) * 17 + lg * 4 + i] = acc[m][i];
  __syncthreads();
  int p = tid >> 4, rh = tid & 15;           // 64 pairs x 16 r-columns
  int pos = p0 + p;
  if (pos < n) {
    float s = 0.f;
#pragma unroll
    for (int ww = 0; ww < 16; ww++) s += red[ww][p * 17 + rh];
    float wgt = wl[ls * T_TOK + pos];
    int t = tok[ls * T_TOK + pos];
    int sl = ls & 1;
    accbf[((size_t)t * 2 + sl) * 16 + rh] = __float2bfloat16(s * wgt);
  }
}

// ---------------- K4: single-pass dense out: y = acc0@w2B[e0]^T + acc1@w2B[e1]^T -------
// grid: tpt(128) x ht(8); block = 64 tokens x 256 cols; slot0 in K<16, slot1 in K>=16.
__global__ __launch_bounds__(256) void k_out(
    const bf16* __restrict__ accbf, const bf16* __restrict__ bw2b,
    const int* __restrict__ selT, float* __restrict__ out)
{
  int tpt = blockIdx.x >> 3;
  int ht  = blockIdx.x & 7;
  int tid = threadIdx.x, w = tid >> 6, l = tid & 63, lm = l & 15, lg = l >> 4;
  int t0 = tpt * 64;
  int tA = t0 + w * 16 + lm;                 // token carried by this lane's A rows
  int r8 = (lg & 1) * 8;
  int slot = lg >> 1;                        // lg 0,1 -> slot0 (k<16); lg 2,3 -> slot1
  short8 A = *reinterpret_cast<const short8*>(accbf + ((size_t)tA * 2 + slot) * 16 + r8);
  int sel = selT[tA];
  int my_e = (slot == 0) ? (sel & 255) : (sel >> 8);

  const short8 ZS = {0, 0, 0, 0, 0, 0, 0, 0};
  const f32x4 zf = {0.f, 0.f, 0.f, 0.f};
  f32x4 y[4][4];
#pragma unroll
  for (int nt = 0; nt < 4; nt++)
#pragma unroll
    for (int hi = 0; hi < 4; hi++) y[nt][hi] = zf;

#pragma unroll
  for (int e = 0; e < 8; e++) {
    short8 Ae = (my_e == e) ? A : ZS;        // per-lane mask
    const bf16* wbe = bw2b + (size_t)e * HD * 16;
#pragma unroll
    for (int nt = 0; nt < 4; nt++) {
#pragma unroll
      for (int hi = 0; hi < 4; hi++) {
        int h = ht * 256 + nt * 64 + hi * 16 + lm;
        short8 B = *reinterpret_cast<const short8*>(wbe + h * 16 + r8);
        y[nt][hi] = MFMA16(Ae, B, y[nt][hi]);
      }
    }
  }
  // D: row = lg*4+i (token), col = lm (h)
#pragma unroll
  for (int nt = 0; nt < 4; nt++)
#pragma unroll
    for (int hi = 0; hi < 4; hi++)
#pragma unroll
      for (int i = 0; i < 4; i++)
        out[(size_t)(t0 + w * 16 + lg * 4 + i) * HD + ht * 256 + nt * 64 + hi * 16 + lm]
            = y[nt][hi][i];
}

// ---------------- launch ----------------
extern "C" void kernel_launch(void* const* d_in, const int* in_sizes, int n_in,
                              void* d_out, int out_size, void* d_ws, size_t ws_size,
                              hipStream_t stream)
{
  const float* x   = (const float*)d_in[0];
  const float* gw  = (const float*)d_in[1];
  const float* w1A = (const float*)d_in[2];
  const float* w1B = (const float*)d_in[3];
  const float* w2A = (const float*)d_in[4];
  const float* w2B = (const float*)d_in[5];
  const float* w3A = (const float*)d_in[6];
  const float* w3B = (const float*)d_in[7];
  float* out = (float*)d_out;
  float* rw  = out + (size_t)T_TOK * HD;

  char* ws = (char*)d_ws;
  bf16*  bw1a3  = (bf16*)(ws + 0);          //  1 MiB   packed [E][64][32][32]
  bf16*  bw1b   = (bf16*)(ws + 1048576);    //  2 MiB   [E][F][R]
  bf16*  bw3b   = (bf16*)(ws + 3145728);    //  2 MiB
  bf16*  bw2apk = (bf16*)(ws + 5242880);    //  2 MiB   A-frag packed [E][256][64][8]
  bf16*  bw2b   = (bf16*)(ws + 7340032);    //  0.5 MiB [E][H][R]
  bf16*  abuf   = (bf16*)(ws + 7864320);    //  4 MiB   dense [T][E][32]
  bf16*  accbf  = (bf16*)(ws + 16252928);   //  0.5 MiB [T][2][16]
  int*   cnt    = (int*) (ws + 16777216);   //  64 B (padded)
  int*   tok    = (int*) (ws + 16777472);   //  0.5 MiB [16][T]
  float* wl     = (float*)(ws + 17301760);  //  0.5 MiB [16][T]
  int*   selT   = (int*) (ws + 17825792);   //  32 KiB  [T]

  k_convert<<<dim3(4096), dim3(256), 0, stream>>>(w1A, w1B, w2A, w2B, w3A, w3B,
                                                  bw1a3, bw1b, bw3b, bw2apk, bw2b, cnt);
  k_stage1 <<<dim3(512),  dim3(256),  0, stream>>>(x, gw, bw1a3, abuf, rw, cnt, tok, wl, selT);
  k_fused  <<<dim3(2048), dim3(1024), 0, stream>>>(abuf, bw1b, bw3b, bw2apk, cnt, tok, wl, accbf);
  k_out    <<<dim3(1024), dim3(256),  0, stream>>>(accbf, bw2b, selT, out);
}

// Round 12
// 183.330 us; speedup vs baseline: 1.2335x; 1.2335x over previous
//
#include <hip/hip_runtime.h>
#include <hip/hip_bf16.h>

typedef __attribute__((ext_vector_type(8))) short short8;
typedef __attribute__((ext_vector_type(4))) float f32x4;
typedef __hip_bfloat16 bf16;

static constexpr int T_TOK = 8192;   // B*S
static constexpr int HD    = 2048;
static constexpr int FD    = 8192;
static constexpr int NE    = 8;

#define MFMA16(a,b,c) __builtin_amdgcn_mfma_f32_16x16x32_bf16((a),(b),(c),0,0,0)

// ---------------- K0: weight convert + pack, zero counts ----------------
__global__ __launch_bounds__(256) void k_convert(
    const float* __restrict__ w1A, const float* __restrict__ w1B,
    const float* __restrict__ w2A, const float* __restrict__ w2B,
    const float* __restrict__ w3A, const float* __restrict__ w3B,
    bf16* __restrict__ bw1a3, bf16* __restrict__ bw1b, bf16* __restrict__ bw3b,
    bf16* __restrict__ bw2apk, bf16* __restrict__ bw2b, int* __restrict__ cnt)
{
  int i = blockIdx.x * 256 + threadIdx.x;          // 0 .. 1048575
  if (blockIdx.x == 0 && threadIdx.x < 16) cnt[threadIdx.x] = 0;
  // straight casts of w1_B / w3_B  [E][F][R] = 1048576 elems
  bw1b[i] = __float2bfloat16(w1B[i]);
  bw3b[i] = __float2bfloat16(w3B[i]);
  { // w2_A [E][R][F] -> A-frag pack for swapped contraction:
    // element j of lane (lg*16+r) in 32-f group ft: f = ft*32+(j>>2)*16+lg*4+(j&3)
    int f = i & (FD - 1); int er = i >> 13; int e = er >> 4; int r = er & 15;
    int ft = f >> 5; int fo = f & 31;
    int sub = fo >> 4; int lg = (fo >> 2) & 3; int j = sub * 4 + (fo & 3);
    int lane = lg * 16 + r;
    bw2apk[((e * 256 + ft) * 64 + lane) * 8 + j] = __float2bfloat16(w2A[i]);
  }
  if (i < 256 * HD) { // pack [w1A;w3A] -> [e][kk(64)][rr(32)][kc(32)]  (2KB tiles)
    int h = i & (HD - 1); int nn = i >> 11; int e = nn >> 5; int rr = nn & 31;
    float v = (rr < 16) ? w1A[(e * 16 + rr) * HD + h] : w3A[(e * 16 + (rr - 16)) * HD + h];
    bw1a3[e * 65536 + (h >> 5) * 1024 + rr * 32 + (h & 31)] = __float2bfloat16(v);
  }
  if (i < NE * HD * 16) bw2b[i] = __float2bfloat16(w2B[i]);  // [E][H][R] cast
}

// ---------------- K1+K2 fused: dense stage-1 + fp32 router + gather ----------------
// 512 blocks x 256 threads (4 waves). 16 tokens/block; wave w does H-slice
// [w*512,(w+1)*512). Cross-wave reduce in 2 expert-halves (33.8 KB LDS).
// NOTE: no min-waves launch bound — forcing 4 blocks/CU caps unified regs at 128
// while live set is ~140 -> inner-loop spill (R11: WRITE_SIZE 4.6->93 MB, 2x slower).
__global__ __launch_bounds__(256) void k_stage1(
    const float* __restrict__ x, const float* __restrict__ gw,
    const bf16* __restrict__ bw1a3, bf16* __restrict__ abuf,
    float* __restrict__ rw_out, int* __restrict__ cnt,
    int* __restrict__ tok, float* __restrict__ wl, int* __restrict__ selT)
{
  int tid = threadIdx.x;
  int w = tid >> 6, l = tid & 63, lm = l & 15, lg = l >> 4;
  int t0 = blockIdx.x * 16;

  __shared__ float redc[4][16 * 132];  // [wave][tok(16) x (128+4 pad)]  33.8 KB
  __shared__ float gred[4][16][8];     // gate partials per wave
  __shared__ float glog[16][8];
  __shared__ int   se0[16], se1[16];
  __shared__ float sw0[16], sw1[16];

  const float* xp = x + (size_t)(t0 + lm) * HD + w * 512 + lg * 8;
  f32x4 acc[8][2];
#pragma unroll
  for (int e = 0; e < 8; e++) { acc[e][0] = {0.f,0.f,0.f,0.f}; acc[e][1] = {0.f,0.f,0.f,0.f}; }
  float g[8];
#pragma unroll
  for (int e = 0; e < 8; e++) g[e] = 0.f;

#pragma unroll 2
  for (int kk2 = 0; kk2 < 16; kk2++) {
    float4 v0 = *reinterpret_cast<const float4*>(xp + kk2 * 32);
    float4 v1 = *reinterpret_cast<const float4*>(xp + kk2 * 32 + 4);
    // fp32 gate dot (exact router numerics); gw loads are wave-coherent (L2-hot)
    const float* gp = gw + w * 512 + kk2 * 32 + lg * 8;
#pragma unroll
    for (int e = 0; e < 8; e++) {
      float4 g0 = *reinterpret_cast<const float4*>(gp + e * HD);
      float4 g1 = *reinterpret_cast<const float4*>(gp + e * HD + 4);
      g[e] += v0.x * g0.x + v0.y * g0.y + v0.z * g0.z + v0.w * g0.w
            + v1.x * g1.x + v1.y * g1.y + v1.z * g1.z + v1.w * g1.w;
    }
    alignas(16) bf16 tmp[8];
    tmp[0] = __float2bfloat16(v0.x); tmp[1] = __float2bfloat16(v0.y);
    tmp[2] = __float2bfloat16(v0.z); tmp[3] = __float2bfloat16(v0.w);
    tmp[4] = __float2bfloat16(v1.x); tmp[5] = __float2bfloat16(v1.y);
    tmp[6] = __float2bfloat16(v1.z); tmp[7] = __float2bfloat16(v1.w);
    short8 af = *reinterpret_cast<const short8*>(tmp);
    const bf16* bt = bw1a3 + (w * 16 + kk2) * 1024 + lg * 8;
#pragma unroll
    for (int e = 0; e < 8; e++) {
      const bf16* be = bt + e * 65536;
      short8 b0 = *reinterpret_cast<const short8*>(be + lm * 32);
      short8 b1 = *reinterpret_cast<const short8*>(be + (lm + 16) * 32);
      acc[e][0] = MFMA16(af, b0, acc[e][0]);
      acc[e][1] = MFMA16(af, b1, acc[e][1]);
    }
  }
  // gate: in-wave reduce over lg (lanes lm, lm+16, lm+32, lm+48)
#pragma unroll
  for (int e = 0; e < 8; e++) {
    g[e] += __shfl_xor(g[e], 16);
    g[e] += __shfl_xor(g[e], 32);
  }
  if (lg == 0) {
#pragma unroll
    for (int e = 0; e < 8; e++) gred[w][lm][e] = g[e];
  }
  // cross-wave reduce + abuf store in 2 expert-halves (reuse redc)
#pragma unroll
  for (int half = 0; half < 2; half++) {
#pragma unroll
    for (int ei = 0; ei < 4; ei++) {
      int e = half * 4 + ei;
#pragma unroll
      for (int i = 0; i < 4; i++) {
        int tt = lg * 4 + i;
        redc[w][tt * 132 + ei * 32 + lm]      = acc[e][0][i];
        redc[w][tt * 132 + ei * 32 + 16 + lm] = acc[e][1][i];
      }
    }
    __syncthreads();
    int c = tid & 127, th = tid >> 7;
#pragma unroll
    for (int j8 = 0; j8 < 8; j8++) {
      int j = th * 8 + j8;
      int o = j * 132 + c;
      float s = redc[0][o] + redc[1][o] + redc[2][o] + redc[3][o];
      abuf[(size_t)(t0 + j) * (NE * 32) + half * 128 + c] = __float2bfloat16(s);
    }
    __syncthreads();
  }
  // gate finalize
  if (tid < 128) {
    int tk = tid >> 3, e = tid & 7;
    glog[tk][e] = gred[0][tk][e] + gred[1][tk][e] + gred[2][tk][e] + gred[3][tk][e];
  }
  __syncthreads();
  if (tid < 16) {
    int t = t0 + tid;
    float m = -1e30f;
#pragma unroll
    for (int e = 0; e < 8; e++) m = fmaxf(m, glog[tid][e]);
    float q[8];
#pragma unroll
    for (int e = 0; e < 8; e++) q[e] = __expf(glog[tid][e] - m);
    int i0 = 0; float b0 = q[0];
#pragma unroll
    for (int e = 1; e < 8; e++) if (q[e] > b0) { b0 = q[e]; i0 = e; }
    int i1 = -1; float b1 = -1.f;
#pragma unroll
    for (int e = 0; e < 8; e++) if (e != i0 && q[e] > b1) { b1 = q[e]; i1 = e; }
    float inv = 1.f / (b0 + b1);
    float r0 = b0 * inv, r1 = b1 * inv;
    rw_out[t * 2 + 0] = r0; rw_out[t * 2 + 1] = r1;
    selT[t] = i0 | (i1 << 8);
    se0[tid] = i0; se1[tid] = i1; sw0[tid] = r0; sw1[tid] = r1;
  }
  __syncthreads();
  if (tid < 16) {
    int ls = tid, e = ls >> 1, slot = ls & 1;
    int c = 0;
#pragma unroll
    for (int jj = 0; jj < 16; jj++)
      c += (slot == 0 ? (se0[jj] == e) : (se1[jj] == e)) ? 1 : 0;
    if (c > 0) {
      int base = atomicAdd(&cnt[ls], c);
      int k = 0;
#pragma unroll
      for (int jj = 0; jj < 16; jj++) {
        bool hit = (slot == 0 ? (se0[jj] == e) : (se1[jj] == e));
        if (hit) {
          tok[ls * T_TOK + base + k] = t0 + jj;
          wl [ls * T_TOK + base + k] = (slot == 0 ? sw0[jj] : sw1[jj]);
          k++;
        }
      }
    }
  }
}

// ---------------- K3: fused F-loop, 16 waves, dbuf prefetch, XCD swizzle ----------------
// 1024 threads / 16 waves; wave w owns F-slice [w*512,(w+1)*512); 64 pairs/block.
// blockIdx: xcd = b&7 -> expert (weights L2-local per XCD); pt = b>>4.
#define LDW(FT, B1, B3, W2) { \
    int f0_ = w * 512 + (FT) * 32; \
    _Pragma("unroll") \
    for (int sub = 0; sub < 2; sub++) { \
      int f_ = f0_ + sub * 16 + lm; \
      B1[sub] = *reinterpret_cast<const short8*>(w1e + f_ * 16 + r8); \
      B3[sub] = *reinterpret_cast<const short8*>(w3e + f_ * 16 + r8); \
    } \
    W2 = *reinterpret_cast<const short8*>(w2e + ((size_t)(f0_ >> 5) * 64 + l) * 8); }

#define CMP(B1, B3, W2) \
  _Pragma("unroll") \
  for (int m = 0; m < 4; m++) { \
    short8 hfrag; \
    _Pragma("unroll") \
    for (int sub = 0; sub < 2; sub++) { \
      f32x4 h1 = MFMA16(B1[sub], A1[m], zf); \
      f32x4 h3 = MFMA16(B3[sub], A3[m], zf); \
      _Pragma("unroll") \
      for (int i = 0; i < 4; i++) { \
        float a = h1[i]; \
        float hv = (a >= 0.f ? a : 0.01f * a) * h3[i]; \
        bf16 hb = __float2bfloat16(hv); \
        hfrag[sub * 4 + i] = *reinterpret_cast<short*>(&hb); \
      } \
    } \
    acc[m] = MFMA16(W2, hfrag, acc[m]); }

__global__ __launch_bounds__(1024) void k_fused(
    const bf16* __restrict__ abuf, const bf16* __restrict__ bw1b,
    const bf16* __restrict__ bw3b, const bf16* __restrict__ bw2apk,
    const int* __restrict__ cnt, const int* __restrict__ tok,
    const float* __restrict__ wl, bf16* __restrict__ accbf)
{
  int b = blockIdx.x;
  int ls = ((b & 7) << 1) | ((b >> 3) & 1);   // expert = XCD
  int pt = b >> 4;
  int n = cnt[ls]; int p0 = pt * 64;
  if (p0 >= n) return;
  int e = ls >> 1;
  int tid = threadIdx.x;
  int w = tid >> 6, l = tid & 63, lm = l & 15, lg = l >> 4;

  __shared__ float red[16][64 * 17];

  const short8 ZS = {0, 0, 0, 0, 0, 0, 0, 0};
  short8 A1[4], A3[4];   // B-operand of swapped MFMA: col=pair(lm), k=lg*8+j (zeros k>=16)
#pragma unroll
  for (int m = 0; m < 4; m++) {
    int pos = p0 + m * 16 + lm; if (pos > n - 1) pos = n - 1;
    int t = tok[ls * T_TOK + pos];
    const bf16* arow = abuf + ((size_t)t * NE + e) * 32;
    if (lg < 2) {
      A1[m] = *reinterpret_cast<const short8*>(arow + lg * 8);
      A3[m] = *reinterpret_cast<const short8*>(arow + 16 + lg * 8);
    } else { A1[m] = ZS; A3[m] = ZS; }
  }
  f32x4 acc[4];
#pragma unroll
  for (int m = 0; m < 4; m++) acc[m] = {0.f, 0.f, 0.f, 0.f};
  const f32x4 zf = {0.f, 0.f, 0.f, 0.f};
  int r8 = (lg & 1) * 8;                      // A-operand k-halves (k>=16 dup, B=0 there)
  const bf16* w1e = bw1b   + (size_t)e * FD * 16;
  const bf16* w3e = bw3b   + (size_t)e * FD * 16;
  const bf16* w2e = bw2apk + (size_t)e * 131072;

  short8 b1A[2], b3A[2], w2A_;
  short8 b1B[2], b3B[2], w2B_;
  LDW(0, b1A, b3A, w2A_);
  for (int ft = 0; ft < 16; ft += 2) {
    LDW(ft + 1, b1B, b3B, w2B_);
    CMP(b1A, b3A, w2A_);
    if (ft + 2 < 16) { LDW(ft + 2, b1A, b3A, w2A_); }
    CMP(b1B, b3B, w2B_);
  }
  // acc[m]: lane holds r = lg*4+i, pair = m*16+lm
#pragma unroll
  for (int m = 0; m < 4; m++)
#pragma unroll
    for (int i = 0; i < 4; i++)
      red[w][(m * 16 + lm) * 17 + lg * 4 + i] = acc[m][i];
  __syncthreads();
  int p = tid >> 4, rh = tid & 15;           // 64 pairs x 16 r-columns
  int pos = p0 + p;
  if (pos < n) {
    float s = 0.f;
#pragma unroll
    for (int ww = 0; ww < 16; ww++) s += red[ww][p * 17 + rh];
    float wgt = wl[ls * T_TOK + pos];
    int t = tok[ls * T_TOK + pos];
    int sl = ls & 1;
    accbf[((size_t)t * 2 + sl) * 16 + rh] = __float2bfloat16(s * wgt);
  }
}

// ---------------- K4: single-pass dense out: y = acc0@w2B[e0]^T + acc1@w2B[e1]^T -------
// grid: tpt(128) x ht(8); block = 64 tokens x 256 cols; slot0 in K<16, slot1 in K>=16.
__global__ __launch_bounds__(256) void k_out(
    const bf16* __restrict__ accbf, const bf16* __restrict__ bw2b,
    const int* __restrict__ selT, float* __restrict__ out)
{
  int tpt = blockIdx.x >> 3;
  int ht  = blockIdx.x & 7;
  int tid = threadIdx.x, w = tid >> 6, l = tid & 63, lm = l & 15, lg = l >> 4;
  int t0 = tpt * 64;
  int tA = t0 + w * 16 + lm;                 // token carried by this lane's A rows
  int r8 = (lg & 1) * 8;
  int slot = lg >> 1;                        // lg 0,1 -> slot0 (k<16); lg 2,3 -> slot1
  short8 A = *reinterpret_cast<const short8*>(accbf + ((size_t)tA * 2 + slot) * 16 + r8);
  int sel = selT[tA];
  int my_e = (slot == 0) ? (sel & 255) : (sel >> 8);

  const short8 ZS = {0, 0, 0, 0, 0, 0, 0, 0};
  const f32x4 zf = {0.f, 0.f, 0.f, 0.f};
  f32x4 y[4][4];
#pragma unroll
  for (int nt = 0; nt < 4; nt++)
#pragma unroll
    for (int hi = 0; hi < 4; hi++) y[nt][hi] = zf;

#pragma unroll
  for (int e = 0; e < 8; e++) {
    short8 Ae = (my_e == e) ? A : ZS;        // per-lane mask
    const bf16* wbe = bw2b + (size_t)e * HD * 16;
#pragma unroll
    for (int nt = 0; nt < 4; nt++) {
#pragma unroll
      for (int hi = 0; hi < 4; hi++) {
        int h = ht * 256 + nt * 64 + hi * 16 + lm;
        short8 B = *reinterpret_cast<const short8*>(wbe + h * 16 + r8);
        y[nt][hi] = MFMA16(Ae, B, y[nt][hi]);
      }
    }
  }
  // D: row = lg*4+i (token), col = lm (h)
#pragma unroll
  for (int nt = 0; nt < 4; nt++)
#pragma unroll
    for (int hi = 0; hi < 4; hi++)
#pragma unroll
      for (int i = 0; i < 4; i++)
        out[(size_t)(t0 + w * 16 + lg * 4 + i) * HD + ht * 256 + nt * 64 + hi * 16 + lm]
            = y[nt][hi][i];
}

// ---------------- launch ----------------
extern "C" void kernel_launch(void* const* d_in, const int* in_sizes, int n_in,
                              void* d_out, int out_size, void* d_ws, size_t ws_size,
                              hipStream_t stream)
{
  const float* x   = (const float*)d_in[0];
  const float* gw  = (const float*)d_in[1];
  const float* w1A = (const float*)d_in[2];
  const float* w1B = (const float*)d_in[3];
  const float* w2A = (const float*)d_in[4];
  const float* w2B = (const float*)d_in[5];
  const float* w3A = (const float*)d_in[6];
  const float* w3B = (const float*)d_in[7];
  float* out = (float*)d_out;
  float* rw  = out + (size_t)T_TOK * HD;

  char* ws = (char*)d_ws;
  bf16*  bw1a3  = (bf16*)(ws + 0);          //  1 MiB   packed [E][64][32][32]
  bf16*  bw1b   = (bf16*)(ws + 1048576);    //  2 MiB   [E][F][R]
  bf16*  bw3b   = (bf16*)(ws + 3145728);    //  2 MiB
  bf16*  bw2apk = (bf16*)(ws + 5242880);    //  2 MiB   A-frag packed [E][256][64][8]
  bf16*  bw2b   = (bf16*)(ws + 7340032);    //  0.5 MiB [E][H][R]
  bf16*  abuf   = (bf16*)(ws + 7864320);    //  4 MiB   dense [T][E][32]
  bf16*  accbf  = (bf16*)(ws + 16252928);   //  0.5 MiB [T][2][16]
  int*   cnt    = (int*) (ws + 16777216);   //  64 B (padded)
  int*   tok    = (int*) (ws + 16777472);   //  0.5 MiB [16][T]
  float* wl     = (float*)(ws + 17301760);  //  0.5 MiB [16][T]
  int*   selT   = (int*) (ws + 17825792);   //  32 KiB  [T]

  k_convert<<<dim3(4096), dim3(256), 0, stream>>>(w1A, w1B, w2A, w2B, w3A, w3B,
                                                  bw1a3, bw1b, bw3b, bw2apk, bw2b, cnt);
  k_stage1 <<<dim3(512),  dim3(256),  0, stream>>>(x, gw, bw1a3, abuf, rw, cnt, tok, wl, selT);
  k_fused  <<<dim3(2048), dim3(1024), 0, stream>>>(abuf, bw1b, bw3b, bw2apk, cnt, tok, wl, accbf);
  k_out    <<<dim3(1024), dim3(256),  0, stream>>>(accbf, bw2b, selT, out);
}

// Round 13
// 182.858 us; speedup vs baseline: 1.2367x; 1.0026x over previous
//
#include <hip/hip_runtime.h>
#include <hip/hip_bf16.h>

typedef __attribute__((ext_vector_type(8))) short short8;
typedef __attribute__((ext_vector_type(4))) float f32x4;
typedef __hip_bfloat16 bf16;

static constexpr int T_TOK = 8192;   // B*S
static constexpr int HD    = 2048;
static constexpr int FD    = 8192;
static constexpr int NE    = 8;

#define MFMA16(a,b,c) __builtin_amdgcn_mfma_f32_16x16x32_bf16((a),(b),(c),0,0,0)

// ---------------- K0: weight convert + pack, zero counts ----------------
__global__ __launch_bounds__(256) void k_convert(
    const float* __restrict__ w1A, const float* __restrict__ w1B,
    const float* __restrict__ w2A, const float* __restrict__ w2B,
    const float* __restrict__ w3A, const float* __restrict__ w3B,
    bf16* __restrict__ bw1a3, bf16* __restrict__ bw1b, bf16* __restrict__ bw3b,
    bf16* __restrict__ bw2apk, bf16* __restrict__ bw2b, int* __restrict__ cnt)
{
  int i = blockIdx.x * 256 + threadIdx.x;          // 0 .. 1048575
  if (blockIdx.x == 0 && threadIdx.x < 16) cnt[threadIdx.x] = 0;
  // straight casts of w1_B / w3_B  [E][F][R] = 1048576 elems
  bw1b[i] = __float2bfloat16(w1B[i]);
  bw3b[i] = __float2bfloat16(w3B[i]);
  { // w2_A [E][R][F] -> A-frag pack for swapped contraction:
    // element j of lane (lg*16+r) in 32-f group ft: f = ft*32+(j>>2)*16+lg*4+(j&3)
    int f = i & (FD - 1); int er = i >> 13; int e = er >> 4; int r = er & 15;
    int ft = f >> 5; int fo = f & 31;
    int sub = fo >> 4; int lg = (fo >> 2) & 3; int j = sub * 4 + (fo & 3);
    int lane = lg * 16 + r;
    bw2apk[((e * 256 + ft) * 64 + lane) * 8 + j] = __float2bfloat16(w2A[i]);
  }
  if (i < 256 * HD) { // pack [w1A;w3A] -> [e][kk(64)][rr(32)][kc(32)]  (2KB tiles)
    int h = i & (HD - 1); int nn = i >> 11; int e = nn >> 5; int rr = nn & 31;
    float v = (rr < 16) ? w1A[(e * 16 + rr) * HD + h] : w3A[(e * 16 + (rr - 16)) * HD + h];
    bw1a3[e * 65536 + (h >> 5) * 1024 + rr * 32 + (h & 31)] = __float2bfloat16(v);
  }
  if (i < NE * HD * 16) bw2b[i] = __float2bfloat16(w2B[i]);  // [E][H][R] cast
}

// ---------------- K1+K2 fused: dense stage-1 + fp32 router + gather ----------------
// 512 blocks x 256 threads (4 waves). 16 tokens/block; wave w does H-slice
// [w*512,(w+1)*512). 4-deep x prefetch (grid caps 8 waves/CU, so VGPR<=~170 free).
// Cross-wave reduce in 2 expert-halves (33.8 KB LDS).
__global__ __launch_bounds__(256) void k_stage1(
    const float* __restrict__ x, const float* __restrict__ gw,
    const bf16* __restrict__ bw1a3, bf16* __restrict__ abuf,
    float* __restrict__ rw_out, int* __restrict__ cnt,
    int* __restrict__ tok, float* __restrict__ wl, int* __restrict__ selT)
{
  int tid = threadIdx.x;
  int w = tid >> 6, l = tid & 63, lm = l & 15, lg = l >> 4;
  int t0 = blockIdx.x * 16;

  __shared__ float redc[4][16 * 132];  // [wave][tok(16) x (128+4 pad)]  33.8 KB
  __shared__ float gred[4][16][8];     // gate partials per wave
  __shared__ float glog[16][8];
  __shared__ int   se0[16], se1[16];
  __shared__ float sw0[16], sw1[16];

  const float* xp = x + (size_t)(t0 + lm) * HD + w * 512 + lg * 8;
  f32x4 acc[8][2];
#pragma unroll
  for (int e = 0; e < 8; e++) { acc[e][0] = {0.f,0.f,0.f,0.f}; acc[e][1] = {0.f,0.f,0.f,0.f}; }
  float g[8];
#pragma unroll
  for (int e = 0; e < 8; e++) g[e] = 0.f;

  // 4-deep x prefetch; xv[p] only ever indexed by unroll-constant p (stays in regs)
  float4 xv0[4], xv1[4];
#pragma unroll
  for (int p = 0; p < 4; p++) {
    xv0[p] = *reinterpret_cast<const float4*>(xp + p * 32);
    xv1[p] = *reinterpret_cast<const float4*>(xp + p * 32 + 4);
  }
  for (int kk4 = 0; kk4 < 16; kk4 += 4) {
#pragma unroll
    for (int p = 0; p < 4; p++) {
      int kk2 = kk4 + p;
      float4 v0 = xv0[p], v1 = xv1[p];
      if (kk4 < 12) {   // prefetch group kk4+4 (wave-uniform branch)
        xv0[p] = *reinterpret_cast<const float4*>(xp + (kk2 + 4) * 32);
        xv1[p] = *reinterpret_cast<const float4*>(xp + (kk2 + 4) * 32 + 4);
      }
      // fp32 gate dot (exact router numerics); gw loads are wave-coherent (L2-hot)
      const float* gp = gw + w * 512 + kk2 * 32 + lg * 8;
#pragma unroll
      for (int e = 0; e < 8; e++) {
        float4 g0 = *reinterpret_cast<const float4*>(gp + e * HD);
        float4 g1 = *reinterpret_cast<const float4*>(gp + e * HD + 4);
        g[e] += v0.x * g0.x + v0.y * g0.y + v0.z * g0.z + v0.w * g0.w
              + v1.x * g1.x + v1.y * g1.y + v1.z * g1.z + v1.w * g1.w;
      }
      alignas(16) bf16 tmp[8];
      tmp[0] = __float2bfloat16(v0.x); tmp[1] = __float2bfloat16(v0.y);
      tmp[2] = __float2bfloat16(v0.z); tmp[3] = __float2bfloat16(v0.w);
      tmp[4] = __float2bfloat16(v1.x); tmp[5] = __float2bfloat16(v1.y);
      tmp[6] = __float2bfloat16(v1.z); tmp[7] = __float2bfloat16(v1.w);
      short8 af = *reinterpret_cast<const short8*>(tmp);
      const bf16* bt = bw1a3 + (w * 16 + kk2) * 1024 + lg * 8;
#pragma unroll
      for (int e = 0; e < 8; e++) {
        const bf16* be = bt + e * 65536;
        short8 b0 = *reinterpret_cast<const short8*>(be + lm * 32);
        short8 b1 = *reinterpret_cast<const short8*>(be + (lm + 16) * 32);
        acc[e][0] = MFMA16(af, b0, acc[e][0]);
        acc[e][1] = MFMA16(af, b1, acc[e][1]);
      }
    }
  }
  // gate: in-wave reduce over lg (lanes lm, lm+16, lm+32, lm+48)
#pragma unroll
  for (int e = 0; e < 8; e++) {
    g[e] += __shfl_xor(g[e], 16);
    g[e] += __shfl_xor(g[e], 32);
  }
  if (lg == 0) {
#pragma unroll
    for (int e = 0; e < 8; e++) gred[w][lm][e] = g[e];
  }
  // cross-wave reduce + abuf store in 2 expert-halves (reuse redc)
#pragma unroll
  for (int half = 0; half < 2; half++) {
#pragma unroll
    for (int ei = 0; ei < 4; ei++) {
      int e = half * 4 + ei;
#pragma unroll
      for (int i = 0; i < 4; i++) {
        int tt = lg * 4 + i;
        redc[w][tt * 132 + ei * 32 + lm]      = acc[e][0][i];
        redc[w][tt * 132 + ei * 32 + 16 + lm] = acc[e][1][i];
      }
    }
    __syncthreads();
    int c = tid & 127, th = tid >> 7;
#pragma unroll
    for (int j8 = 0; j8 < 8; j8++) {
      int j = th * 8 + j8;
      int o = j * 132 + c;
      float s = redc[0][o] + redc[1][o] + redc[2][o] + redc[3][o];
      abuf[(size_t)(t0 + j) * (NE * 32) + half * 128 + c] = __float2bfloat16(s);
    }
    __syncthreads();
  }
  // gate finalize
  if (tid < 128) {
    int tk = tid >> 3, e = tid & 7;
    glog[tk][e] = gred[0][tk][e] + gred[1][tk][e] + gred[2][tk][e] + gred[3][tk][e];
  }
  __syncthreads();
  if (tid < 16) {
    int t = t0 + tid;
    float m = -1e30f;
#pragma unroll
    for (int e = 0; e < 8; e++) m = fmaxf(m, glog[tid][e]);
    float q[8];
#pragma unroll
    for (int e = 0; e < 8; e++) q[e] = __expf(glog[tid][e] - m);
    int i0 = 0; float b0 = q[0];
#pragma unroll
    for (int e = 1; e < 8; e++) if (q[e] > b0) { b0 = q[e]; i0 = e; }
    int i1 = -1; float b1 = -1.f;
#pragma unroll
    for (int e = 0; e < 8; e++) if (e != i0 && q[e] > b1) { b1 = q[e]; i1 = e; }
    float inv = 1.f / (b0 + b1);
    float r0 = b0 * inv, r1 = b1 * inv;
    rw_out[t * 2 + 0] = r0; rw_out[t * 2 + 1] = r1;
    selT[t] = i0 | (i1 << 8);
    se0[tid] = i0; se1[tid] = i1; sw0[tid] = r0; sw1[tid] = r1;
  }
  __syncthreads();
  if (tid < 16) {
    int ls = tid, e = ls >> 1, slot = ls & 1;
    int c = 0;
#pragma unroll
    for (int jj = 0; jj < 16; jj++)
      c += (slot == 0 ? (se0[jj] == e) : (se1[jj] == e)) ? 1 : 0;
    if (c > 0) {
      int base = atomicAdd(&cnt[ls], c);
      int k = 0;
#pragma unroll
      for (int jj = 0; jj < 16; jj++) {
        bool hit = (slot == 0 ? (se0[jj] == e) : (se1[jj] == e));
        if (hit) {
          tok[ls * T_TOK + base + k] = t0 + jj;
          wl [ls * T_TOK + base + k] = (slot == 0 ? sw0[jj] : sw1[jj]);
          k++;
        }
      }
    }
  }
}

// ---------------- K3: fused F-loop, 16 waves, dbuf prefetch, XCD swizzle ----------------
// 1024 threads / 16 waves; wave w owns F-slice [w*512,(w+1)*512); 64 pairs/block.
// blockIdx: xcd = b&7 -> expert (weights L2-local per XCD); pt = b>>4.
#define LDW(FT, B1, B3, W2) { \
    int f0_ = w * 512 + (FT) * 32; \
    _Pragma("unroll") \
    for (int sub = 0; sub < 2; sub++) { \
      int f_ = f0_ + sub * 16 + lm; \
      B1[sub] = *reinterpret_cast<const short8*>(w1e + f_ * 16 + r8); \
      B3[sub] = *reinterpret_cast<const short8*>(w3e + f_ * 16 + r8); \
    } \
    W2 = *reinterpret_cast<const short8*>(w2e + ((size_t)(f0_ >> 5) * 64 + l) * 8); }

#define CMP(B1, B3, W2) \
  _Pragma("unroll") \
  for (int m = 0; m < 4; m++) { \
    short8 hfrag; \
    _Pragma("unroll") \
    for (int sub = 0; sub < 2; sub++) { \
      f32x4 h1 = MFMA16(B1[sub], A1[m], zf); \
      f32x4 h3 = MFMA16(B3[sub], A3[m], zf); \
      _Pragma("unroll") \
      for (int i = 0; i < 4; i++) { \
        float a = h1[i]; \
        float hv = (a >= 0.f ? a : 0.01f * a) * h3[i]; \
        bf16 hb = __float2bfloat16(hv); \
        hfrag[sub * 4 + i] = *reinterpret_cast<short*>(&hb); \
      } \
    } \
    acc[m] = MFMA16(W2, hfrag, acc[m]); }

__global__ __launch_bounds__(1024) void k_fused(
    const bf16* __restrict__ abuf, const bf16* __restrict__ bw1b,
    const bf16* __restrict__ bw3b, const bf16* __restrict__ bw2apk,
    const int* __restrict__ cnt, const int* __restrict__ tok,
    const float* __restrict__ wl, bf16* __restrict__ accbf)
{
  int b = blockIdx.x;
  int ls = ((b & 7) << 1) | ((b >> 3) & 1);   // expert = XCD
  int pt = b >> 4;
  int n = cnt[ls]; int p0 = pt * 64;
  if (p0 >= n) return;
  int e = ls >> 1;
  int tid = threadIdx.x;
  int w = tid >> 6, l = tid & 63, lm = l & 15, lg = l >> 4;

  __shared__ float red[16][64 * 17];

  const short8 ZS = {0, 0, 0, 0, 0, 0, 0, 0};
  short8 A1[4], A3[4];   // B-operand of swapped MFMA: col=pair(lm), k=lg*8+j (zeros k>=16)
#pragma unroll
  for (int m = 0; m < 4; m++) {
    int pos = p0 + m * 16 + lm; if (pos > n - 1) pos = n - 1;
    int t = tok[ls * T_TOK + pos];
    const bf16* arow = abuf + ((size_t)t * NE + e) * 32;
    if (lg < 2) {
      A1[m] = *reinterpret_cast<const short8*>(arow + lg * 8);
      A3[m] = *reinterpret_cast<const short8*>(arow + 16 + lg * 8);
    } else { A1[m] = ZS; A3[m] = ZS; }
  }
  f32x4 acc[4];
#pragma unroll
  for (int m = 0; m < 4; m++) acc[m] = {0.f, 0.f, 0.f, 0.f};
  const f32x4 zf = {0.f, 0.f, 0.f, 0.f};
  int r8 = (lg & 1) * 8;                      // A-operand k-halves (k>=16 dup, B=0 there)
  const bf16* w1e = bw1b   + (size_t)e * FD * 16;
  const bf16* w3e = bw3b   + (size_t)e * FD * 16;
  const bf16* w2e = bw2apk + (size_t)e * 131072;

  short8 b1A[2], b3A[2], w2A_;
  short8 b1B[2], b3B[2], w2B_;
  LDW(0, b1A, b3A, w2A_);
  for (int ft = 0; ft < 16; ft += 2) {
    LDW(ft + 1, b1B, b3B, w2B_);
    CMP(b1A, b3A, w2A_);
    if (ft + 2 < 16) { LDW(ft + 2, b1A, b3A, w2A_); }
    CMP(b1B, b3B, w2B_);
  }
  // acc[m]: lane holds r = lg*4+i, pair = m*16+lm
#pragma unroll
  for (int m = 0; m < 4; m++)
#pragma unroll
    for (int i = 0; i < 4; i++)
      red[w][(m * 16 + lm) * 17 + lg * 4 + i] = acc[m][i];
  __syncthreads();
  int p = tid >> 4, rh = tid & 15;           // 64 pairs x 16 r-columns
  int pos = p0 + p;
  if (pos < n) {
    float s = 0.f;
#pragma unroll
    for (int ww = 0; ww < 16; ww++) s += red[ww][p * 17 + rh];
    float wgt = wl[ls * T_TOK + pos];
    int t = tok[ls * T_TOK + pos];
    int sl = ls & 1;
    accbf[((size_t)t * 2 + sl) * 16 + rh] = __float2bfloat16(s * wgt);
  }
}

// ---------------- K4: single-pass dense out: y = acc0@w2B[e0]^T + acc1@w2B[e1]^T -------
// grid: tpt(128) x ht(8); block = 64 tokens x 256 cols; slot0 in K<16, slot1 in K>=16.
__global__ __launch_bounds__(256) void k_out(
    const bf16* __restrict__ accbf, const bf16* __restrict__ bw2b,
    const int* __restrict__ selT, float* __restrict__ out)
{
  int tpt = blockIdx.x >> 3;
  int ht  = blockIdx.x & 7;
  int tid = threadIdx.x, w = tid >> 6, l = tid & 63, lm = l & 15, lg = l >> 4;
  int t0 = tpt * 64;
  int tA = t0 + w * 16 + lm;                 // token carried by this lane's A rows
  int r8 = (lg & 1) * 8;
  int slot = lg >> 1;                        // lg 0,1 -> slot0 (k<16); lg 2,3 -> slot1
  short8 A = *reinterpret_cast<const short8*>(accbf + ((size_t)tA * 2 + slot) * 16 + r8);
  int sel = selT[tA];
  int my_e = (slot == 0) ? (sel & 255) : (sel >> 8);

  const short8 ZS = {0, 0, 0, 0, 0, 0, 0, 0};
  const f32x4 zf = {0.f, 0.f, 0.f, 0.f};
  f32x4 y[4][4];
#pragma unroll
  for (int nt = 0; nt < 4; nt++)
#pragma unroll
    for (int hi = 0; hi < 4; hi++) y[nt][hi] = zf;

#pragma unroll
  for (int e = 0; e < 8; e++) {
    short8 Ae = (my_e == e) ? A : ZS;        // per-lane mask
    const bf16* wbe = bw2b + (size_t)e * HD * 16;
#pragma unroll
    for (int nt = 0; nt < 4; nt++) {
#pragma unroll
      for (int hi = 0; hi < 4; hi++) {
        int h = ht * 256 + nt * 64 + hi * 16 + lm;
        short8 B = *reinterpret_cast<const short8*>(wbe + h * 16 + r8);
        y[nt][hi] = MFMA16(Ae, B, y[nt][hi]);
      }
    }
  }
  // D: row = lg*4+i (token), col = lm (h)
#pragma unroll
  for (int nt = 0; nt < 4; nt++)
#pragma unroll
    for (int hi = 0; hi < 4; hi++)
#pragma unroll
      for (int i = 0; i < 4; i++)
        out[(size_t)(t0 + w * 16 + lg * 4 + i) * HD + ht * 256 + nt * 64 + hi * 16 + lm]
            = y[nt][hi][i];
}

// ---------------- launch ----------------
extern "C" void kernel_launch(void* const* d_in, const int* in_sizes, int n_in,
                              void* d_out, int out_size, void* d_ws, size_t ws_size,
                              hipStream_t stream)
{
  const float* x   = (const float*)d_in[0];
  const float* gw  = (const float*)d_in[1];
  const float* w1A = (const float*)d_in[2];
  const float* w1B = (const float*)d_in[3];
  const float* w2A = (const float*)d_in[4];
  const float* w2B = (const float*)d_in[5];
  const float* w3A = (const float*)d_in[6];
  const float* w3B = (const float*)d_in[7];
  float* out = (float*)d_out;
  float* rw  = out + (size_t)T_TOK * HD;

  char* ws = (char*)d_ws;
  bf16*  bw1a3  = (bf16*)(ws + 0);          //  1 MiB   packed [E][64][32][32]
  bf16*  bw1b   = (bf16*)(ws + 1048576);    //  2 MiB   [E][F][R]
  bf16*  bw3b   = (bf16*)(ws + 3145728);    //  2 MiB
  bf16*  bw2apk = (bf16*)(ws + 5242880);    //  2 MiB   A-frag packed [E][256][64][8]
  bf16*  bw2b   = (bf16*)(ws + 7340032);    //  0.5 MiB [E][H][R]
  bf16*  abuf   = (bf16*)(ws + 7864320);    //  4 MiB   dense [T][E][32]
  bf16*  accbf  = (bf16*)(ws + 16252928);   //  0.5 MiB [T][2][16]
  int*   cnt    = (int*) (ws + 16777216);   //  64 B (padded)
  int*   tok    = (int*) (ws + 16777472);   //  0.5 MiB [16][T]
  float* wl     = (float*)(ws + 17301760);  //  0.5 MiB [16][T]
  int*   selT   = (int*) (ws + 17825792);   //  32 KiB  [T]

  k_convert<<<dim3(4096), dim3(256), 0, stream>>>(w1A, w1B, w2A, w2B, w3A, w3B,
                                                  bw1a3, bw1b, bw3b, bw2apk, bw2b, cnt);
  k_stage1 <<<dim3(512),  dim3(256),  0, stream>>>(x, gw, bw1a3, abuf, rw, cnt, tok, wl, selT);
  k_fused  <<<dim3(2048), dim3(1024), 0, stream>>>(abuf, bw1b, bw3b, bw2apk, cnt, tok, wl, accbf);
  k_out    <<<dim3(1024), dim3(256),  0, stream>>>(accbf, bw2b, selT, out);
}

// Round 14
// 178.011 us; speedup vs baseline: 1.2704x; 1.0272x over previous
//
#include <hip/hip_runtime.h>
#include <hip/hip_bf16.h>

typedef __attribute__((ext_vector_type(8))) short short8;
typedef __attribute__((ext_vector_type(4))) float f32x4;
typedef __hip_bfloat16 bf16;

static constexpr int T_TOK = 8192;   // B*S
static constexpr int HD    = 2048;
static constexpr int FD    = 8192;
static constexpr int NE    = 8;

#define MFMA16(a,b,c) __builtin_amdgcn_mfma_f32_16x16x32_bf16((a),(b),(c),0,0,0)

// ---------------- K0: weight convert + pack, zero counts ----------------
__global__ __launch_bounds__(256) void k_convert(
    const float* __restrict__ w1A, const float* __restrict__ w1B,
    const float* __restrict__ w2A, const float* __restrict__ w2B,
    const float* __restrict__ w3A, const float* __restrict__ w3B,
    bf16* __restrict__ bw1a3, bf16* __restrict__ bw1b, bf16* __restrict__ bw3b,
    bf16* __restrict__ bw2apk, bf16* __restrict__ bw2b, int* __restrict__ cnt)
{
  int i = blockIdx.x * 256 + threadIdx.x;          // 0 .. 1048575
  if (blockIdx.x == 0 && threadIdx.x < 16) cnt[threadIdx.x] = 0;
  // straight casts of w1_B / w3_B  [E][F][R] = 1048576 elems
  bw1b[i] = __float2bfloat16(w1B[i]);
  bw3b[i] = __float2bfloat16(w3B[i]);
  { // w2_A [E][R][F] -> A-frag pack for swapped contraction:
    // element j of lane (lg*16+r) in 32-f group ft: f = ft*32+(j>>2)*16+lg*4+(j&3)
    int f = i & (FD - 1); int er = i >> 13; int e = er >> 4; int r = er & 15;
    int ft = f >> 5; int fo = f & 31;
    int sub = fo >> 4; int lg = (fo >> 2) & 3; int j = sub * 4 + (fo & 3);
    int lane = lg * 16 + r;
    bw2apk[((e * 256 + ft) * 64 + lane) * 8 + j] = __float2bfloat16(w2A[i]);
  }
  if (i < 256 * HD) { // pack [w1A;w3A] -> [e][kk(64)][rr(32)][kc(32)]  (2KB tiles)
    int h = i & (HD - 1); int nn = i >> 11; int e = nn >> 5; int rr = nn & 31;
    float v = (rr < 16) ? w1A[(e * 16 + rr) * HD + h] : w3A[(e * 16 + (rr - 16)) * HD + h];
    bw1a3[e * 65536 + (h >> 5) * 1024 + rr * 32 + (h & 31)] = __float2bfloat16(v);
  }
  if (i < NE * HD * 16) bw2b[i] = __float2bfloat16(w2B[i]);  // [E][H][R] cast
}

// ---------------- K1: router (fp32) + block-aggregated gather + selT ----------------
// 512 blocks x 256 threads; 16 tokens/block, 16 sublanes/token.
__global__ __launch_bounds__(256) void k_router(
    const float* __restrict__ x, const float* __restrict__ gw,
    float* __restrict__ rw_out, int* __restrict__ cnt,
    int* __restrict__ tok, float* __restrict__ wl, int* __restrict__ selT)
{
  int tid = threadIdx.x;
  int j = tid >> 4;            // token within block (0..15)
  int r = tid & 15;            // sublane (0..15)
  int t = blockIdx.x * 16 + j;

  const float4* xr = reinterpret_cast<const float4*>(x + (size_t)t * HD);
  float p[8];
#pragma unroll
  for (int e = 0; e < 8; e++) p[e] = 0.f;
#pragma unroll 4
  for (int it = 0; it < 32; it++) {
    float4 xv = xr[it * 16 + r];
#pragma unroll
    for (int e = 0; e < 8; e++) {
      float4 gv = reinterpret_cast<const float4*>(gw + e * HD)[it * 16 + r];
      p[e] += xv.x * gv.x + xv.y * gv.y + xv.z * gv.z + xv.w * gv.w;
    }
  }
#pragma unroll
  for (int e = 0; e < 8; e++) {
#pragma unroll
    for (int m = 1; m <= 8; m <<= 1) p[e] += __shfl_xor(p[e], m);
  }

  __shared__ int   se0[16], se1[16];
  __shared__ float sw0[16], sw1[16];
  if (r == 0) {
    float m = -1e30f;
#pragma unroll
    for (int e = 0; e < 8; e++) m = fmaxf(m, p[e]);
    float q[8];
#pragma unroll
    for (int e = 0; e < 8; e++) q[e] = __expf(p[e] - m);
    int i0 = 0; float b0 = q[0];
#pragma unroll
    for (int e = 1; e < 8; e++) if (q[e] > b0) { b0 = q[e]; i0 = e; }
    int i1 = -1; float b1 = -1.f;
#pragma unroll
    for (int e = 0; e < 8; e++) if (e != i0 && q[e] > b1) { b1 = q[e]; i1 = e; }
    float inv = 1.f / (b0 + b1);
    float r0 = b0 * inv, r1 = b1 * inv;
    rw_out[t * 2 + 0] = r0; rw_out[t * 2 + 1] = r1;
    selT[t] = i0 | (i1 << 8);
    se0[j] = i0; se1[j] = i1; sw0[j] = r0; sw1[j] = r1;
  }
  __syncthreads();
  if (tid < 16) {
    int ls = tid, e = ls >> 1, slot = ls & 1;
    int c = 0;
#pragma unroll
    for (int jj = 0; jj < 16; jj++)
      c += (slot == 0 ? (se0[jj] == e) : (se1[jj] == e)) ? 1 : 0;
    if (c > 0) {
      int base = atomicAdd(&cnt[ls], c);
      int k = 0;
#pragma unroll
      for (int jj = 0; jj < 16; jj++) {
        bool hit = (slot == 0 ? (se0[jj] == e) : (se1[jj] == e));
        if (hit) {
          tok[ls * T_TOK + base + k] = blockIdx.x * 16 + jj;
          wl [ls * T_TOK + base + k] = (slot == 0 ? sw0[jj] : sw1[jj]);
          k++;
        }
      }
    }
  }
}

// ---------------- K3: fused gathered stage1 (Phase A) + F-loop (Phase B) ----------------
// 1024 threads / 16 waves. Block = (ls, 64 token slots).
// Phase A: 4 tok-groups x 4 K-slices -> a = x_rows @ [w1A;w3A][e]^T, LDS fp32 reduce.
// Phase B: wave w owns F-slice [w*512,(w+1)*512); identical to prior k_fused.
#define LDW(FT, B1, B3, W2) { \
    int f0_ = w * 512 + (FT) * 32; \
    _Pragma("unroll") \
    for (int sub = 0; sub < 2; sub++) { \
      int f_ = f0_ + sub * 16 + lm; \
      B1[sub] = *reinterpret_cast<const short8*>(w1e + f_ * 16 + r8); \
      B3[sub] = *reinterpret_cast<const short8*>(w3e + f_ * 16 + r8); \
    } \
    W2 = *reinterpret_cast<const short8*>(w2e + ((size_t)(f0_ >> 5) * 64 + l) * 8); }

#define CMP(B1, B3, W2) \
  _Pragma("unroll") \
  for (int m = 0; m < 4; m++) { \
    short8 hfrag; \
    _Pragma("unroll") \
    for (int sub = 0; sub < 2; sub++) { \
      f32x4 h1 = MFMA16(B1[sub], A1[m], zf); \
      f32x4 h3 = MFMA16(B3[sub], A3[m], zf); \
      _Pragma("unroll") \
      for (int i = 0; i < 4; i++) { \
        float a = h1[i]; \
        float hv = (a >= 0.f ? a : 0.01f * a) * h3[i]; \
        bf16 hb = __float2bfloat16(hv); \
        hfrag[sub * 4 + i] = *reinterpret_cast<short*>(&hb); \
      } \
    } \
    acc[m] = MFMA16(W2, hfrag, acc[m]); }

__global__ __launch_bounds__(1024) void k_fused(
    const float* __restrict__ x, const bf16* __restrict__ bw1a3,
    const bf16* __restrict__ bw1b, const bf16* __restrict__ bw3b,
    const bf16* __restrict__ bw2apk,
    const int* __restrict__ cnt, const int* __restrict__ tok,
    const float* __restrict__ wl, bf16* __restrict__ accbf)
{
  int b = blockIdx.x;
  int ls = ((b & 7) << 1) | ((b >> 3) & 1);   // expert = XCD
  int pt = b >> 4;
  int n = cnt[ls]; int p0 = pt * 64;
  if (p0 >= n) return;
  int e = ls >> 1;
  int tid = threadIdx.x;
  int w = tid >> 6, l = tid & 63, lm = l & 15, lg = l >> 4;

  __shared__ int toks[64];
  __shared__ __align__(16) bf16 aT[64 * 40];                 // 5 KB a1a3 tile
  __shared__ __align__(16) char uni[16 * 64 * 17 * 4];       // 69.6 KB union
  float* part = reinterpret_cast<float*>(uni);               // [4][64][33] Phase A
  float* red  = reinterpret_cast<float*>(uni);               // [16][64*17] Phase B

  if (tid < 64) {
    int pos = p0 + tid; if (pos > n - 1) pos = n - 1;
    toks[tid] = tok[ls * T_TOK + pos];
  }
  __syncthreads();

  const f32x4 zf = {0.f, 0.f, 0.f, 0.f};
  // ---- Phase A: gathered stage-1, one expert, 4 loads + 2 MFMA per iter ----
  {
    int tg = w >> 2, ks = w & 3;              // token-group, K-slice
    const float* xp = x + (size_t)toks[tg * 16 + lm] * HD + ks * 512 + lg * 8;
    const bf16* be = bw1a3 + e * 65536 + ks * 16384 + lg * 8;
    f32x4 a0 = zf, a1 = zf;
#pragma unroll 4
    for (int kk2 = 0; kk2 < 16; kk2++) {
      float4 v0 = *reinterpret_cast<const float4*>(xp + kk2 * 32);
      float4 v1 = *reinterpret_cast<const float4*>(xp + kk2 * 32 + 4);
      alignas(16) bf16 tmp[8];
      tmp[0] = __float2bfloat16(v0.x); tmp[1] = __float2bfloat16(v0.y);
      tmp[2] = __float2bfloat16(v0.z); tmp[3] = __float2bfloat16(v0.w);
      tmp[4] = __float2bfloat16(v1.x); tmp[5] = __float2bfloat16(v1.y);
      tmp[6] = __float2bfloat16(v1.z); tmp[7] = __float2bfloat16(v1.w);
      short8 af = *reinterpret_cast<const short8*>(tmp);
      short8 b0 = *reinterpret_cast<const short8*>(be + kk2 * 1024 + lm * 32);
      short8 b1 = *reinterpret_cast<const short8*>(be + kk2 * 1024 + (lm + 16) * 32);
      a0 = MFMA16(af, b0, a0);
      a1 = MFMA16(af, b1, a1);
    }
    // C: col=lm (rr), row(token-in-group)=lg*4+i
#pragma unroll
    for (int i = 0; i < 4; i++) {
      int row = tg * 16 + lg * 4 + i;
      part[(ks * 64 + row) * 33 + lm]      = a0[i];
      part[(ks * 64 + row) * 33 + 16 + lm] = a1[i];
    }
  }
  __syncthreads();
  { // reduce 4 K-slices -> aT (bf16); 1024 threads x 2 elems
    int tokr = tid >> 4, c2 = (tid & 15) * 2;
    float s0 = 0.f, s1 = 0.f;
#pragma unroll
    for (int ks = 0; ks < 4; ks++) {
      s0 += part[(ks * 64 + tokr) * 33 + c2];
      s1 += part[(ks * 64 + tokr) * 33 + c2 + 1];
    }
    aT[tokr * 40 + c2]     = __float2bfloat16(s0);
    aT[tokr * 40 + c2 + 1] = __float2bfloat16(s1);
  }
  __syncthreads();

  // ---- Phase B: F-loop (identical structure to prior k_fused) ----
  const short8 ZS = {0, 0, 0, 0, 0, 0, 0, 0};
  short8 A1[4], A3[4];   // B-operand of swapped MFMA: col=pair(lm), k=lg*8+j (zeros k>=16)
#pragma unroll
  for (int m = 0; m < 4; m++) {
    if (lg < 2) {
      A1[m] = *reinterpret_cast<const short8*>(&aT[(m * 16 + lm) * 40 + lg * 8]);
      A3[m] = *reinterpret_cast<const short8*>(&aT[(m * 16 + lm) * 40 + 16 + lg * 8]);
    } else { A1[m] = ZS; A3[m] = ZS; }
  }
  f32x4 acc[4];
#pragma unroll
  for (int m = 0; m < 4; m++) acc[m] = zf;
  int r8 = (lg & 1) * 8;                      // A-operand k-halves (k>=16 dup, B=0 there)
  const bf16* w1e = bw1b   + (size_t)e * FD * 16;
  const bf16* w3e = bw3b   + (size_t)e * FD * 16;
  const bf16* w2e = bw2apk + (size_t)e * 131072;

  short8 b1A[2], b3A[2], w2A_;
  short8 b1B[2], b3B[2], w2B_;
  LDW(0, b1A, b3A, w2A_);
  for (int ft = 0; ft < 16; ft += 2) {
    LDW(ft + 1, b1B, b3B, w2B_);
    CMP(b1A, b3A, w2A_);
    if (ft + 2 < 16) { LDW(ft + 2, b1A, b3A, w2A_); }
    CMP(b1B, b3B, w2B_);
  }
  // acc[m]: lane holds r = lg*4+i, pair = m*16+lm
#pragma unroll
  for (int m = 0; m < 4; m++)
#pragma unroll
    for (int i = 0; i < 4; i++)
      red[w * 1088 + (m * 16 + lm) * 17 + lg * 4 + i] = acc[m][i];
  __syncthreads();
  int p = tid >> 4, rh = tid & 15;           // 64 pairs x 16 r-columns
  int pos = p0 + p;
  if (pos < n) {
    float s = 0.f;
#pragma unroll
    for (int ww = 0; ww < 16; ww++) s += red[ww * 1088 + p * 17 + rh];
    float wgt = wl[ls * T_TOK + pos];
    int t = toks[p];
    int sl = ls & 1;
    accbf[((size_t)t * 2 + sl) * 16 + rh] = __float2bfloat16(s * wgt);
  }
}

// ---------------- K4: single-pass dense out: y = acc0@w2B[e0]^T + acc1@w2B[e1]^T -------
// grid: tpt(128) x ht(8); block = 64 tokens x 256 cols; slot0 in K<16, slot1 in K>=16.
__global__ __launch_bounds__(256) void k_out(
    const bf16* __restrict__ accbf, const bf16* __restrict__ bw2b,
    const int* __restrict__ selT, float* __restrict__ out)
{
  int tpt = blockIdx.x >> 3;
  int ht  = blockIdx.x & 7;
  int tid = threadIdx.x, w = tid >> 6, l = tid & 63, lm = l & 15, lg = l >> 4;
  int t0 = tpt * 64;
  int tA = t0 + w * 16 + lm;                 // token carried by this lane's A rows
  int r8 = (lg & 1) * 8;
  int slot = lg >> 1;                        // lg 0,1 -> slot0 (k<16); lg 2,3 -> slot1
  short8 A = *reinterpret_cast<const short8*>(accbf + ((size_t)tA * 2 + slot) * 16 + r8);
  int sel = selT[tA];
  int my_e = (slot == 0) ? (sel & 255) : (sel >> 8);

  const short8 ZS = {0, 0, 0, 0, 0, 0, 0, 0};
  const f32x4 zf = {0.f, 0.f, 0.f, 0.f};
  f32x4 y[4][4];
#pragma unroll
  for (int nt = 0; nt < 4; nt++)
#pragma unroll
    for (int hi = 0; hi < 4; hi++) y[nt][hi] = zf;

#pragma unroll
  for (int e = 0; e < 8; e++) {
    short8 Ae = (my_e == e) ? A : ZS;        // per-lane mask
    const bf16* wbe = bw2b + (size_t)e * HD * 16;
#pragma unroll
    for (int nt = 0; nt < 4; nt++) {
#pragma unroll
      for (int hi = 0; hi < 4; hi++) {
        int h = ht * 256 + nt * 64 + hi * 16 + lm;
        short8 B = *reinterpret_cast<const short8*>(wbe + h * 16 + r8);
        y[nt][hi] = MFMA16(Ae, B, y[nt][hi]);
      }
    }
  }
  // D: row = lg*4+i (token), col = lm (h)
#pragma unroll
  for (int nt = 0; nt < 4; nt++)
#pragma unroll
    for (int hi = 0; hi < 4; hi++)
#pragma unroll
      for (int i = 0; i < 4; i++)
        out[(size_t)(t0 + w * 16 + lg * 4 + i) * HD + ht * 256 + nt * 64 + hi * 16 + lm]
            = y[nt][hi][i];
}

// ---------------- launch ----------------
extern "C" void kernel_launch(void* const* d_in, const int* in_sizes, int n_in,
                              void* d_out, int out_size, void* d_ws, size_t ws_size,
                              hipStream_t stream)
{
  const float* x   = (const float*)d_in[0];
  const float* gw  = (const float*)d_in[1];
  const float* w1A = (const float*)d_in[2];
  const float* w1B = (const float*)d_in[3];
  const float* w2A = (const float*)d_in[4];
  const float* w2B = (const float*)d_in[5];
  const float* w3A = (const float*)d_in[6];
  const float* w3B = (const float*)d_in[7];
  float* out = (float*)d_out;
  float* rw  = out + (size_t)T_TOK * HD;

  char* ws = (char*)d_ws;
  bf16*  bw1a3  = (bf16*)(ws + 0);          //  1 MiB   packed [E][64][32][32]
  bf16*  bw1b   = (bf16*)(ws + 1048576);    //  2 MiB   [E][F][R]
  bf16*  bw3b   = (bf16*)(ws + 3145728);    //  2 MiB
  bf16*  bw2apk = (bf16*)(ws + 5242880);    //  2 MiB   A-frag packed [E][256][64][8]
  bf16*  bw2b   = (bf16*)(ws + 7340032);    //  0.5 MiB [E][H][R]
  bf16*  accbf  = (bf16*)(ws + 16252928);   //  0.5 MiB [T][2][16]
  int*   cnt    = (int*) (ws + 16777216);   //  64 B (padded)
  int*   tok    = (int*) (ws + 16777472);   //  0.5 MiB [16][T]
  float* wl     = (float*)(ws + 17301760);  //  0.5 MiB [16][T]
  int*   selT   = (int*) (ws + 17825792);   //  32 KiB  [T]

  k_convert<<<dim3(4096), dim3(256), 0, stream>>>(w1A, w1B, w2A, w2B, w3A, w3B,
                                                  bw1a3, bw1b, bw3b, bw2apk, bw2b, cnt);
  k_router <<<dim3(512),  dim3(256),  0, stream>>>(x, gw, rw, cnt, tok, wl, selT);
  k_fused  <<<dim3(2048), dim3(1024), 0, stream>>>(x, bw1a3, bw1b, bw3b, bw2apk,
                                                   cnt, tok, wl, accbf);
  k_out    <<<dim3(1024), dim3(256),  0, stream>>>(accbf, bw2b, selT, out);
}

// Round 15
// 153.677 us; speedup vs baseline: 1.4715x; 1.1583x over previous
//
#include <hip/hip_runtime.h>
#include <hip/hip_bf16.h>

typedef __attribute__((ext_vector_type(8))) short short8;
typedef __attribute__((ext_vector_type(4))) float f32x4;
typedef __hip_bfloat16 bf16;

static constexpr int T_TOK = 8192;   // B*S
static constexpr int HD    = 2048;
static constexpr int FD    = 8192;
static constexpr int NE    = 8;

#define MFMA16(a,b,c) __builtin_amdgcn_mfma_f32_16x16x32_bf16((a),(b),(c),0,0,0)

// ---------------- K0: weight convert + pack, zero counts ----------------
__global__ __launch_bounds__(256) void k_convert(
    const float* __restrict__ w1A, const float* __restrict__ w1B,
    const float* __restrict__ w2A, const float* __restrict__ w2B,
    const float* __restrict__ w3A, const float* __restrict__ w3B,
    bf16* __restrict__ bw1a3, bf16* __restrict__ bw1b, bf16* __restrict__ bw3b,
    bf16* __restrict__ bw2apk, bf16* __restrict__ bw2b, int* __restrict__ cnt)
{
  int i = blockIdx.x * 256 + threadIdx.x;          // 0 .. 1048575
  if (blockIdx.x == 0 && threadIdx.x < 16) cnt[threadIdx.x] = 0;
  // straight casts of w1_B / w3_B  [E][F][R] = 1048576 elems
  bw1b[i] = __float2bfloat16(w1B[i]);
  bw3b[i] = __float2bfloat16(w3B[i]);
  { // w2_A [E][R][F] -> A-frag pack for swapped contraction:
    // element j of lane (lg*16+r) in 32-f group ft: f = ft*32+(j>>2)*16+lg*4+(j&3)
    int f = i & (FD - 1); int er = i >> 13; int e = er >> 4; int r = er & 15;
    int ft = f >> 5; int fo = f & 31;
    int sub = fo >> 4; int lg = (fo >> 2) & 3; int j = sub * 4 + (fo & 3);
    int lane = lg * 16 + r;
    bw2apk[((e * 256 + ft) * 64 + lane) * 8 + j] = __float2bfloat16(w2A[i]);
  }
  if (i < 256 * HD) { // pack [w1A;w3A] -> [e][kk(64)][rr(32)][kc(32)]  (2KB tiles)
    int h = i & (HD - 1); int nn = i >> 11; int e = nn >> 5; int rr = nn & 31;
    float v = (rr < 16) ? w1A[(e * 16 + rr) * HD + h] : w3A[(e * 16 + (rr - 16)) * HD + h];
    bw1a3[e * 65536 + (h >> 5) * 1024 + rr * 32 + (h & 31)] = __float2bfloat16(v);
  }
  if (i < NE * HD * 16) bw2b[i] = __float2bfloat16(w2B[i]);  // [E][H][R] cast
}

// ---------------- K1: router (fp32) + gather + selT + bf16-x side product ----------------
// 512 blocks x 256 threads; 16 tokens/block, 16 sublanes/token.
__global__ __launch_bounds__(256) void k_router(
    const float* __restrict__ x, const float* __restrict__ gw,
    float* __restrict__ rw_out, int* __restrict__ cnt,
    int* __restrict__ tok, float* __restrict__ wl, int* __restrict__ selT,
    bf16* __restrict__ bx, int use_bx)
{
  int tid = threadIdx.x;
  int j = tid >> 4;            // token within block (0..15)
  int r = tid & 15;            // sublane (0..15)
  int t = blockIdx.x * 16 + j;

  const float4* xr = reinterpret_cast<const float4*>(x + (size_t)t * HD);
  float p[8];
#pragma unroll
  for (int e = 0; e < 8; e++) p[e] = 0.f;
#pragma unroll 4
  for (int it = 0; it < 32; it++) {
    float4 xv = xr[it * 16 + r];
#pragma unroll
    for (int e = 0; e < 8; e++) {
      float4 gv = reinterpret_cast<const float4*>(gw + e * HD)[it * 16 + r];
      p[e] += xv.x * gv.x + xv.y * gv.y + xv.z * gv.z + xv.w * gv.w;
    }
    if (use_bx) {   // bf16 copy of x (free read: already in regs)
      alignas(8) bf16 tb[4];
      tb[0] = __float2bfloat16(xv.x); tb[1] = __float2bfloat16(xv.y);
      tb[2] = __float2bfloat16(xv.z); tb[3] = __float2bfloat16(xv.w);
      *reinterpret_cast<uint2*>(bx + (size_t)t * HD + (it * 16 + r) * 4) =
          *reinterpret_cast<const uint2*>(tb);
    }
  }
#pragma unroll
  for (int e = 0; e < 8; e++) {
#pragma unroll
    for (int m = 1; m <= 8; m <<= 1) p[e] += __shfl_xor(p[e], m);
  }

  __shared__ int   se0[16], se1[16];
  __shared__ float sw0[16], sw1[16];
  if (r == 0) {
    float m = -1e30f;
#pragma unroll
    for (int e = 0; e < 8; e++) m = fmaxf(m, p[e]);
    float q[8];
#pragma unroll
    for (int e = 0; e < 8; e++) q[e] = __expf(p[e] - m);
    int i0 = 0; float b0 = q[0];
#pragma unroll
    for (int e = 1; e < 8; e++) if (q[e] > b0) { b0 = q[e]; i0 = e; }
    int i1 = -1; float b1 = -1.f;
#pragma unroll
    for (int e = 0; e < 8; e++) if (e != i0 && q[e] > b1) { b1 = q[e]; i1 = e; }
    float inv = 1.f / (b0 + b1);
    float r0 = b0 * inv, r1 = b1 * inv;
    rw_out[t * 2 + 0] = r0; rw_out[t * 2 + 1] = r1;
    selT[t] = i0 | (i1 << 8);
    se0[j] = i0; se1[j] = i1; sw0[j] = r0; sw1[j] = r1;
  }
  __syncthreads();
  if (tid < 16) {
    int ls = tid, e = ls >> 1, slot = ls & 1;
    int c = 0;
#pragma unroll
    for (int jj = 0; jj < 16; jj++)
      c += (slot == 0 ? (se0[jj] == e) : (se1[jj] == e)) ? 1 : 0;
    if (c > 0) {
      int base = atomicAdd(&cnt[ls], c);
      int k = 0;
#pragma unroll
      for (int jj = 0; jj < 16; jj++) {
        bool hit = (slot == 0 ? (se0[jj] == e) : (se1[jj] == e));
        if (hit) {
          tok[ls * T_TOK + base + k] = blockIdx.x * 16 + jj;
          wl [ls * T_TOK + base + k] = (slot == 0 ? sw0[jj] : sw1[jj]);
          k++;
        }
      }
    }
  }
}

// ---------------- K3: fused gathered stage1 (Phase A) + F-loop (Phase B) ----------------
// 1024 threads / 16 waves. Block = (ls, 32 token slots) -> 512 live blocks (2/CU).
// Phase A: 2 tok-groups x 8 K-slices(256) -> a = x_rows @ [w1A;w3A][e]^T, LDS reduce.
// Phase B: wave w owns F-slice [w*512,(w+1)*512); 2 m-groups.
#define LDW(FT, B1, B3, W2) { \
    int f0_ = w * 512 + (FT) * 32; \
    _Pragma("unroll") \
    for (int sub = 0; sub < 2; sub++) { \
      int f_ = f0_ + sub * 16 + lm; \
      B1[sub] = *reinterpret_cast<const short8*>(w1e + f_ * 16 + r8); \
      B3[sub] = *reinterpret_cast<const short8*>(w3e + f_ * 16 + r8); \
    } \
    W2 = *reinterpret_cast<const short8*>(w2e + ((size_t)(f0_ >> 5) * 64 + l) * 8); }

#define CMP(B1, B3, W2) \
  _Pragma("unroll") \
  for (int m = 0; m < 2; m++) { \
    short8 hfrag; \
    _Pragma("unroll") \
    for (int sub = 0; sub < 2; sub++) { \
      f32x4 h1 = MFMA16(B1[sub], A1[m], zf); \
      f32x4 h3 = MFMA16(B3[sub], A3[m], zf); \
      _Pragma("unroll") \
      for (int i = 0; i < 4; i++) { \
        float a = h1[i]; \
        float hv = (a >= 0.f ? a : 0.01f * a) * h3[i]; \
        bf16 hb = __float2bfloat16(hv); \
        hfrag[sub * 4 + i] = *reinterpret_cast<short*>(&hb); \
      } \
    } \
    acc[m] = MFMA16(W2, hfrag, acc[m]); }

__global__ __launch_bounds__(1024) void k_fused(
    const float* __restrict__ x, const bf16* __restrict__ bx, int use_bx,
    const bf16* __restrict__ bw1a3,
    const bf16* __restrict__ bw1b, const bf16* __restrict__ bw3b,
    const bf16* __restrict__ bw2apk,
    const int* __restrict__ cnt, const int* __restrict__ tok,
    const float* __restrict__ wl, bf16* __restrict__ accbf)
{
  int b = blockIdx.x;
  int ls = ((b & 7) << 1) | ((b >> 3) & 1);   // expert = XCD
  int pt = b >> 4;                            // 0..255
  int n = cnt[ls]; int p0 = pt * 32;
  if (p0 >= n) return;
  int e = ls >> 1;
  int tid = threadIdx.x;
  int w = tid >> 6, l = tid & 63, lm = l & 15, lg = l >> 4;

  __shared__ int toks[32];
  __shared__ __align__(16) bf16 aT[32 * 40];                 // 2.5 KB a1a3 tile
  __shared__ __align__(16) char uni[16 * 32 * 17 * 4];       // 34.8 KB union
  float* part = reinterpret_cast<float*>(uni);               // [8][32][33] Phase A
  float* red  = reinterpret_cast<float*>(uni);               // [16][32*17] Phase B

  if (tid < 32) {
    int pos = p0 + tid; if (pos > n - 1) pos = n - 1;
    toks[tid] = tok[ls * T_TOK + pos];
  }
  __syncthreads();

  const f32x4 zf = {0.f, 0.f, 0.f, 0.f};
  // ---- Phase A: gathered stage-1, one expert ----
  {
    int tg = w >> 3, ks = w & 7;              // token-group (2), K-slice (8 x 256)
    const bf16* be = bw1a3 + e * 65536 + ks * 8192 + lg * 8;
    f32x4 a0 = zf, a1 = zf;
    if (use_bx) {
      const bf16* xp = bx + (size_t)toks[tg * 16 + lm] * HD + ks * 256 + lg * 8;
#pragma unroll
      for (int kk2 = 0; kk2 < 8; kk2++) {
        short8 af = *reinterpret_cast<const short8*>(xp + kk2 * 32);
        short8 b0 = *reinterpret_cast<const short8*>(be + kk2 * 1024 + lm * 32);
        short8 b1 = *reinterpret_cast<const short8*>(be + kk2 * 1024 + (lm + 16) * 32);
        a0 = MFMA16(af, b0, a0);
        a1 = MFMA16(af, b1, a1);
      }
    } else {
      const float* xp = x + (size_t)toks[tg * 16 + lm] * HD + ks * 256 + lg * 8;
#pragma unroll
      for (int kk2 = 0; kk2 < 8; kk2++) {
        float4 v0 = *reinterpret_cast<const float4*>(xp + kk2 * 32);
        float4 v1 = *reinterpret_cast<const float4*>(xp + kk2 * 32 + 4);
        alignas(16) bf16 tmp[8];
        tmp[0] = __float2bfloat16(v0.x); tmp[1] = __float2bfloat16(v0.y);
        tmp[2] = __float2bfloat16(v0.z); tmp[3] = __float2bfloat16(v0.w);
        tmp[4] = __float2bfloat16(v1.x); tmp[5] = __float2bfloat16(v1.y);
        tmp[6] = __float2bfloat16(v1.z); tmp[7] = __float2bfloat16(v1.w);
        short8 af = *reinterpret_cast<const short8*>(tmp);
        short8 b0 = *reinterpret_cast<const short8*>(be + kk2 * 1024 + lm * 32);
        short8 b1 = *reinterpret_cast<const short8*>(be + kk2 * 1024 + (lm + 16) * 32);
        a0 = MFMA16(af, b0, a0);
        a1 = MFMA16(af, b1, a1);
      }
    }
    // C: col=lm (rr), row(token-in-group)=lg*4+i
#pragma unroll
    for (int i = 0; i < 4; i++) {
      int row = tg * 16 + lg * 4 + i;
      part[(ks * 32 + row) * 33 + lm]      = a0[i];
      part[(ks * 32 + row) * 33 + 16 + lm] = a1[i];
    }
  }
  __syncthreads();
  { // reduce 8 K-slices -> aT (bf16); 1024 threads x 1 elem
    int tokr = tid >> 5, c = tid & 31;
    float s = 0.f;
#pragma unroll
    for (int ks = 0; ks < 8; ks++) s += part[(ks * 32 + tokr) * 33 + c];
    aT[tokr * 40 + c] = __float2bfloat16(s);
  }
  __syncthreads();

  // ---- Phase B: F-loop ----
  const short8 ZS = {0, 0, 0, 0, 0, 0, 0, 0};
  short8 A1[2], A3[2];   // B-operand of swapped MFMA: col=pair(lm), k=lg*8+j (zeros k>=16)
#pragma unroll
  for (int m = 0; m < 2; m++) {
    if (lg < 2) {
      A1[m] = *reinterpret_cast<const short8*>(&aT[(m * 16 + lm) * 40 + lg * 8]);
      A3[m] = *reinterpret_cast<const short8*>(&aT[(m * 16 + lm) * 40 + 16 + lg * 8]);
    } else { A1[m] = ZS; A3[m] = ZS; }
  }
  f32x4 acc[2];
  acc[0] = zf; acc[1] = zf;
  int r8 = (lg & 1) * 8;                      // A-operand k-halves (k>=16 dup, B=0 there)
  const bf16* w1e = bw1b   + (size_t)e * FD * 16;
  const bf16* w3e = bw3b   + (size_t)e * FD * 16;
  const bf16* w2e = bw2apk + (size_t)e * 131072;

  short8 b1A[2], b3A[2], w2A_;
  short8 b1B[2], b3B[2], w2B_;
  LDW(0, b1A, b3A, w2A_);
  for (int ft = 0; ft < 16; ft += 2) {
    LDW(ft + 1, b1B, b3B, w2B_);
    CMP(b1A, b3A, w2A_);
    if (ft + 2 < 16) { LDW(ft + 2, b1A, b3A, w2A_); }
    CMP(b1B, b3B, w2B_);
  }
  // acc[m]: lane holds r = lg*4+i, pair = m*16+lm
#pragma unroll
  for (int m = 0; m < 2; m++)
#pragma unroll
    for (int i = 0; i < 4; i++)
      red[w * 544 + (m * 16 + lm) * 17 + lg * 4 + i] = acc[m][i];
  __syncthreads();
  if (tid < 512) {
    int p = tid >> 4, rh = tid & 15;         // 32 pairs x 16 r-columns
    int pos = p0 + p;
    if (pos < n) {
      float s = 0.f;
#pragma unroll
      for (int ww = 0; ww < 16; ww++) s += red[ww * 544 + p * 17 + rh];
      float wgt = wl[ls * T_TOK + pos];
      int t = toks[p];
      int sl = ls & 1;
      accbf[((size_t)t * 2 + sl) * 16 + rh] = __float2bfloat16(s * wgt);
    }
  }
}

// ---------------- K4: single-pass dense out: y = acc0@w2B[e0]^T + acc1@w2B[e1]^T -------
// grid: tpt(128) x ht(8); block = 64 tokens x 256 cols; slot0 in K<16, slot1 in K>=16.
__global__ __launch_bounds__(256) void k_out(
    const bf16* __restrict__ accbf, const bf16* __restrict__ bw2b,
    const int* __restrict__ selT, float* __restrict__ out)
{
  int tpt = blockIdx.x >> 3;
  int ht  = blockIdx.x & 7;
  int tid = threadIdx.x, w = tid >> 6, l = tid & 63, lm = l & 15, lg = l >> 4;
  int t0 = tpt * 64;
  int tA = t0 + w * 16 + lm;                 // token carried by this lane's A rows
  int r8 = (lg & 1) * 8;
  int slot = lg >> 1;                        // lg 0,1 -> slot0 (k<16); lg 2,3 -> slot1
  short8 A = *reinterpret_cast<const short8*>(accbf + ((size_t)tA * 2 + slot) * 16 + r8);
  int sel = selT[tA];
  int my_e = (slot == 0) ? (sel & 255) : (sel >> 8);

  const short8 ZS = {0, 0, 0, 0, 0, 0, 0, 0};
  const f32x4 zf = {0.f, 0.f, 0.f, 0.f};
  f32x4 y[4][4];
#pragma unroll
  for (int nt = 0; nt < 4; nt++)
#pragma unroll
    for (int hi = 0; hi < 4; hi++) y[nt][hi] = zf;

#pragma unroll
  for (int e = 0; e < 8; e++) {
    short8 Ae = (my_e == e) ? A : ZS;        // per-lane mask
    const bf16* wbe = bw2b + (size_t)e * HD * 16;
#pragma unroll
    for (int nt = 0; nt < 4; nt++) {
#pragma unroll
      for (int hi = 0; hi < 4; hi++) {
        int h = ht * 256 + nt * 64 + hi * 16 + lm;
        short8 B = *reinterpret_cast<const short8*>(wbe + h * 16 + r8);
        y[nt][hi] = MFMA16(Ae, B, y[nt][hi]);
      }
    }
  }
  // D: row = lg*4+i (token), col = lm (h)
#pragma unroll
  for (int nt = 0; nt < 4; nt++)
#pragma unroll
    for (int hi = 0; hi < 4; hi++)
#pragma unroll
      for (int i = 0; i < 4; i++)
        out[(size_t)(t0 + w * 16 + lg * 4 + i) * HD + ht * 256 + nt * 64 + hi * 16 + lm]
            = y[nt][hi][i];
}

// ---------------- launch ----------------
extern "C" void kernel_launch(void* const* d_in, const int* in_sizes, int n_in,
                              void* d_out, int out_size, void* d_ws, size_t ws_size,
                              hipStream_t stream)
{
  const float* x   = (const float*)d_in[0];
  const float* gw  = (const float*)d_in[1];
  const float* w1A = (const float*)d_in[2];
  const float* w1B = (const float*)d_in[3];
  const float* w2A = (const float*)d_in[4];
  const float* w2B = (const float*)d_in[5];
  const float* w3A = (const float*)d_in[6];
  const float* w3B = (const float*)d_in[7];
  float* out = (float*)d_out;
  float* rw  = out + (size_t)T_TOK * HD;

  char* ws = (char*)d_ws;
  bf16*  bw1a3  = (bf16*)(ws + 0);          //  1 MiB   packed [E][64][32][32]
  bf16*  bw1b   = (bf16*)(ws + 1048576);    //  2 MiB   [E][F][R]
  bf16*  bw3b   = (bf16*)(ws + 3145728);    //  2 MiB
  bf16*  bw2apk = (bf16*)(ws + 5242880);    //  2 MiB   A-frag packed [E][256][64][8]
  bf16*  bw2b   = (bf16*)(ws + 7340032);    //  0.5 MiB [E][H][R]
  bf16*  accbf  = (bf16*)(ws + 16252928);   //  0.5 MiB [T][2][16]
  int*   cnt    = (int*) (ws + 16777216);   //  64 B (padded)
  int*   tok    = (int*) (ws + 16777472);   //  0.5 MiB [16][T]
  float* wl     = (float*)(ws + 17301760);  //  0.5 MiB [16][T]
  int*   selT   = (int*) (ws + 17825792);   //  32 KiB  [T]
  bf16*  bx     = (bf16*)(ws + 18874368);   //  32 MiB  [T][H] bf16 x (optional)
  int use_bx = (ws_size >= (size_t)18874368 + 33554432) ? 1 : 0;

  k_convert<<<dim3(4096), dim3(256), 0, stream>>>(w1A, w1B, w2A, w2B, w3A, w3B,
                                                  bw1a3, bw1b, bw3b, bw2apk, bw2b, cnt);
  k_router <<<dim3(512),  dim3(256),  0, stream>>>(x, gw, rw, cnt, tok, wl, selT, bx, use_bx);
  k_fused  <<<dim3(4096), dim3(1024), 0, stream>>>(x, bx, use_bx, bw1a3, bw1b, bw3b, bw2apk,
                                                   cnt, tok, wl, accbf);
  k_out    <<<dim3(1024), dim3(256),  0, stream>>>(accbf, bw2b, selT, out);
}